// Round 6
// baseline (215.400 us; speedup 1.0000x reference)
//
#include <hip/hip_runtime.h>
#include <hip/hip_bf16.h>
#include <stdint.h>

#define H_DIM 4096
#define I_DIM 11008
#define NGH   32    // H/128 groups (gate/up)
#define NGI   86    // I/128 groups (down)

typedef __attribute__((ext_vector_type(8))) short short8;
typedef __attribute__((ext_vector_type(4))) short s16x4;
typedef __attribute__((ext_vector_type(4))) float f32x4;
typedef __attribute__((ext_vector_type(4))) int   i32x4;

#define AS1 __attribute__((address_space(1)))
#define AS3 __attribute__((address_space(3)))

// async global->LDS DMA, 16B per lane: dst(base wave-uniform) + lane*16 <- *src(per-lane)
static __device__ __forceinline__ void gload_lds16(const int* src, int* dst) {
  __builtin_amdgcn_global_load_lds((const AS1 int*)src, (AS3 int*)dst, 16, 0, 0);
}

static __device__ __forceinline__ short f2bf(float f) {
  union { __hip_bfloat16 b; short s; } u;
  u.b = __float2bfloat16(f);
  return u.s;
}

__global__ void xcvt_kernel(const float* __restrict__ x, short* __restrict__ xb) {
  int i = (blockIdx.x * 256 + threadIdx.x) * 4;
  f32x4 v = *(const f32x4*)(x + i);
  s16x4 o;
  o[0] = f2bf(v[0]); o[1] = f2bf(v[1]); o[2] = f2bf(v[2]); o[3] = f2bf(v[3]);
  *(s16x4*)(xb + i) = o;
}

// ---------------- phase1: gate+up GEMM + SwiGLU ----------------
// Grid: I/16 blocks x 512 thr (8 waves). Block = 16 I-rows, K=4096 in 16
// windows of 256. Wave w: proj p=w>>2 (0=gate,1=up), k-slice q=w&3 (64 wide).
// Weights staged raw int32 into LDS (dbuf) via 1KB global_load_lds bursts,
// XOR slot-swizzle (16B slots, ^ (row&7)) on src+read for bank-conflict-free
// ds_read_b128.
__global__ __launch_bounds__(512, 4) void phase1_kernel(
    const short* __restrict__ xb,
    const int* __restrict__ gq, const float* __restrict__ gsc, const float* __restrict__ gze,
    const int* __restrict__ uq, const float* __restrict__ usc, const float* __restrict__ uze,
    short* __restrict__ hb)
{
  __shared__ int ldsq[2][2][16][256];   // [buf][proj][row][k] = 64 KB
  const int n0   = blockIdx.x * 16;
  const int w    = threadIdx.x >> 6;
  const int l    = threadIdx.x & 63;
  const int col  = l & 15;
  const int krow = l >> 4;
  const int pp   = w >> 2;             // 0 gate, 1 up
  const int q    = w & 3;              // k-slice within window

  const int*   qb  = pp ? uq  : gq;
  const float* scp = pp ? usc : gsc;
  const float* zep = pp ? uze : gze;
  const int    iidx = n0 + col;

  f32x4 acc[4];
#pragma unroll
  for (int c = 0; c < 4; ++c)
#pragma unroll
    for (int r = 0; r < 4; ++r) acc[c][r] = 0.f;

  // per-wave staging sources: 4 rows, lane fetches pre-swizzled 16B slot
  const int rq = q * 4;
  const int* srow[4];
#pragma unroll
  for (int rr = 0; rr < 4; ++rr)
    srow[rr] = qb + (size_t)(n0 + rq + rr) * H_DIM + ((l ^ ((rq + rr) & 7)) << 2);

  // prologue: stage window 0 into buf 0
#pragma unroll
  for (int rr = 0; rr < 4; ++rr)
    gload_lds16(srow[rr], &ldsq[0][pp][rq + rr][0]);
  __syncthreads();

  const int* lbase = &ldsq[0][pp][col][0];

#pragma unroll 1
  for (int kw = 0; kw < 16; ++kw) {
    const int bf = kw & 1;
    // 1) a-fragments first (oldest in vmem queue -> their waits never drain stage)
    short8 a[2][4];
#pragma unroll
    for (int ss = 0; ss < 2; ++ss) {
      const int kg = kw * 256 + q * 64 + ss * 32 + krow * 8;
#pragma unroll
      for (int c = 0; c < 4; ++c)
        a[ss][c] = *(const short8*)(xb + (size_t)(c * 16 + col) * H_DIM + kg);
    }
    // 2) stage next window (drained only at end-of-window barrier)
    if (kw + 1 < 16) {
#pragma unroll
      for (int rr = 0; rr < 4; ++rr)
        gload_lds16(srow[rr] + (kw + 1) * 256, &ldsq[bf ^ 1][pp][rq + rr][0]);
    }
    // 3) group params (group = kw*2 + upper/lower half of window)
    const int g = kw * 2 + (q >> 1);
    const float sv = scp[iidx * NGH + g];
    const float zv = zep[iidx * NGH + g] * sv;
    // 4) LDS -> dequant -> MFMA
    const int* lb = lbase + bf * 8192;   // buf stride = 2*16*256 ints
#pragma unroll
    for (int ss = 0; ss < 2; ++ss) {
      const int slot0 = q * 16 + ss * 8 + krow * 2;
      i32x4 lo = *(const i32x4*)(lb + ((slot0 ^ (col & 7)) << 2));
      i32x4 hi = *(const i32x4*)(lb + (((slot0 + 1) ^ (col & 7)) << 2));
      short8 b;
#pragma unroll
      for (int j = 0; j < 4; ++j) {
        b[j]     = f2bf((float)lo[j] * sv - zv);
        b[j + 4] = f2bf((float)hi[j] * sv - zv);
      }
#pragma unroll
      for (int c = 0; c < 4; ++c)
        acc[c] = __builtin_amdgcn_mfma_f32_16x16x32_bf16(a[ss][c], b, acc[c], 0, 0, 0);
    }
    __syncthreads();   // implicit vmcnt(0): stage for kw+1 guaranteed landed
  }

  // epilogue: cross-wave K reduce + SwiGLU (reuse LDS as f32 scratch)
  float* red = (float*)&ldsq[0][0][0][0];   // [8][4][4][64] = 32 KB
#pragma unroll
  for (int c = 0; c < 4; ++c)
#pragma unroll
    for (int r = 0; r < 4; ++r)
      red[((w * 16 + c * 4 + r) << 6) + l] = acc[c][r];
  __syncthreads();
  if (threadIdx.x < 256) {
    const int c2 = threadIdx.x >> 6;
    const int ll = threadIdx.x & 63;
#pragma unroll
    for (int r = 0; r < 4; ++r) {
      float gs_ = 0.f, us_ = 0.f;
#pragma unroll
      for (int ww = 0; ww < 4; ++ww) {
        gs_ += red[(((ww    ) * 16 + c2 * 4 + r) << 6) + ll];
        us_ += red[(((ww + 4) * 16 + c2 * 4 + r) << 6) + ll];
      }
      const float hv = gs_ / (1.f + __expf(-gs_)) * us_;   // silu(g)*u
      const int m  = c2 * 16 + (ll >> 4) * 4 + r;          // C/D: row=(l>>4)*4+r
      const int ii = n0 + (ll & 15);                       //      col=l&15
      hb[(size_t)m * I_DIM + ii] = f2bf(hv);
    }
  }
}

// ---------------- phase2: down GEMM, split-K x4 ----------------
// Grid: 256 tiles x 4 splits = 1024 blocks x 512 thr. Block = 16 H-rows,
// split K-range in windows of 256 (splits 0-2: 11 windows, split 3: 10).
// Wave w = k-slice (32 wide) within window. Same staging/swizzle as phase1.
__global__ __launch_bounds__(512, 4) void phase2_kernel(
    const short* __restrict__ hb,
    const int* __restrict__ dq, const float* __restrict__ dsc, const float* __restrict__ dze,
    float* __restrict__ part)
{
  __shared__ int ldsq[2][16][256];     // 32 KB
  const int tile  = blockIdx.x & 255;
  const int split = blockIdx.x >> 8;
  const int n0   = tile * 16;
  const int w    = threadIdx.x >> 6;
  const int l    = threadIdx.x & 63;
  const int col  = l & 15;
  const int krow = l >> 4;
  const int nidx = n0 + col;

  const int kw0 = split * 11;
  const int nkw = (split < 3) ? 11 : 10;

  f32x4 acc[4];
#pragma unroll
  for (int c = 0; c < 4; ++c)
#pragma unroll
    for (int r = 0; r < 4; ++r) acc[c][r] = 0.f;

  const int* srow[2];
#pragma unroll
  for (int rr = 0; rr < 2; ++rr) {
    const int r = w * 2 + rr;
    srow[rr] = dq + (size_t)(n0 + r) * I_DIM + kw0 * 256 + ((l ^ (r & 7)) << 2);
  }

#pragma unroll
  for (int rr = 0; rr < 2; ++rr)
    gload_lds16(srow[rr], &ldsq[0][w * 2 + rr][0]);
  __syncthreads();

#pragma unroll 1
  for (int ki = 0; ki < nkw; ++ki) {
    const int kw = kw0 + ki;
    const int bf = ki & 1;
    short8 a[4];
    const int kg = kw * 256 + w * 32 + krow * 8;
#pragma unroll
    for (int c = 0; c < 4; ++c)
      a[c] = *(const short8*)(hb + (size_t)(c * 16 + col) * I_DIM + kg);
    if (ki + 1 < nkw) {
#pragma unroll
      for (int rr = 0; rr < 2; ++rr)
        gload_lds16(srow[rr] + (ki + 1) * 256, &ldsq[bf ^ 1][w * 2 + rr][0]);
    }
    const int g = kw * 2 + (w >> 2);
    const float sv = dsc[nidx * NGI + g];
    const float zv = dze[nidx * NGI + g] * sv;
    const int* lb = &ldsq[bf][col][0];
    const int slot0 = w * 8 + krow * 2;
    i32x4 lo = *(const i32x4*)(lb + ((slot0 ^ (col & 7)) << 2));
    i32x4 hi = *(const i32x4*)(lb + (((slot0 + 1) ^ (col & 7)) << 2));
    short8 b;
#pragma unroll
    for (int j = 0; j < 4; ++j) {
      b[j]     = f2bf((float)lo[j] * sv - zv);
      b[j + 4] = f2bf((float)hi[j] * sv - zv);
    }
#pragma unroll
    for (int c = 0; c < 4; ++c)
      acc[c] = __builtin_amdgcn_mfma_f32_16x16x32_bf16(a[c], b, acc[c], 0, 0, 0);
    __syncthreads();
  }

  float* red = (float*)&ldsq[0][0][0];   // [8][4][4][64] = 32 KB
#pragma unroll
  for (int c = 0; c < 4; ++c)
#pragma unroll
    for (int r = 0; r < 4; ++r)
      red[((w * 16 + c * 4 + r) << 6) + l] = acc[c][r];
  __syncthreads();
  if (threadIdx.x < 256) {
    const int c2 = threadIdx.x >> 6;
    const int ll = threadIdx.x & 63;
    float* po = part + (size_t)split * (64 * H_DIM);
#pragma unroll
    for (int r = 0; r < 4; ++r) {
      float s = 0.f;
#pragma unroll
      for (int ww = 0; ww < 8; ++ww)
        s += red[((ww * 16 + c2 * 4 + r) << 6) + ll];
      const int m  = c2 * 16 + (ll >> 4) * 4 + r;
      const int nn = n0 + (ll & 15);
      po[(size_t)m * H_DIM + nn] = s;
    }
  }
}

__global__ void reduce4_kernel(const float* __restrict__ part, float* __restrict__ out) {
  const int idx = (blockIdx.x * 256 + threadIdx.x) * 4;
  const int S = 64 * H_DIM;
  f32x4 s0 = *(const f32x4*)(part + idx);
  f32x4 s1 = *(const f32x4*)(part + S + idx);
  f32x4 s2 = *(const f32x4*)(part + 2 * S + idx);
  f32x4 s3 = *(const f32x4*)(part + 3 * S + idx);
  f32x4 r = (s0 + s1) + (s2 + s3);
  *(f32x4*)(out + idx) = r;
}

extern "C" void kernel_launch(void* const* d_in, const int* in_sizes, int n_in,
                              void* d_out, int out_size, void* d_ws, size_t ws_size,
                              hipStream_t stream) {
  const float* x  = (const float*)d_in[0];
  const int*   gq = (const int*)d_in[1];
  const float* gs = (const float*)d_in[2];
  const float* gz = (const float*)d_in[3];
  const int*   uq = (const int*)d_in[4];
  const float* us = (const float*)d_in[5];
  const float* uz = (const float*)d_in[6];
  const int*   dq = (const int*)d_in[7];
  const float* ds = (const float*)d_in[8];
  const float* dz = (const float*)d_in[9];
  float* out = (float*)d_out;

  // ws: [0,512K) x_bf16 [64][4096]; [512K,+1.376M) h_bf16 [64][11008];
  //     then f32 partials [4][64][4096] (4 MB)
  short* xb = (short*)d_ws;
  short* hb = (short*)((char*)d_ws + (size_t)64 * H_DIM * 2);
  float* part = (float*)((char*)d_ws + (size_t)64 * H_DIM * 2 + (size_t)64 * I_DIM * 2);

  xcvt_kernel<<<(64 * H_DIM) / 1024, 256, 0, stream>>>(x, xb);
  phase1_kernel<<<I_DIM / 16, 512, 0, stream>>>(xb, gq, gs, gz, uq, us, uz, hb);
  phase2_kernel<<<(H_DIM / 16) * 4, 512, 0, stream>>>(hb, dq, ds, dz, part);
  reduce4_kernel<<<(64 * H_DIM) / 1024, 256, 0, stream>>>(part, out);
}